// Round 1
// baseline (14319.800 us; speedup 1.0000x reference)
//
#include <hip/hip_runtime.h>
#include <hip/hip_bf16.h>

#define NB 32
#define NT 512
#define ND 1024
#define NH 1024
#define G3 3072

typedef __attribute__((ext_vector_type(8))) short short8;
typedef __attribute__((ext_vector_type(4))) float f32x4;
typedef __attribute__((ext_vector_type(4))) unsigned short us4;

static __device__ __forceinline__ unsigned short f2bf(float f) {
    union { float f; unsigned u; } v; v.f = f;
    if ((v.u & 0x7fffffffu) > 0x7f800000u) return (unsigned short)((v.u >> 16) | 0x0040u);
    unsigned u = v.u + 0x7fffu + ((v.u >> 16) & 1u);
    return (unsigned short)(u >> 16);
}
static __device__ __forceinline__ float bf2f(unsigned short s) {
    union { unsigned u; float f; } v; v.u = ((unsigned)s) << 16; return v.f;
}

// ---------------- f32 -> bf16 conversion (vectorized) ----------------
__global__ __launch_bounds__(256) void cvt_bf16_v4(const float4* __restrict__ src,
                                                   us4* __restrict__ dst, int n4) {
    for (int i = blockIdx.x * 256 + threadIdx.x; i < n4; i += gridDim.x * 256) {
        float4 v = src[i];
        us4 o;
        o.x = f2bf(v.x); o.y = f2bf(v.y); o.z = f2bf(v.z); o.w = f2bf(v.w);
        dst[i] = o;
    }
}

// ---------------- init hidden state (f32 master + bf16 shadow) ----------------
__global__ __launch_bounds__(256) void init_h(const float* __restrict__ hid,
                                              float* __restrict__ h0f, unsigned short* __restrict__ h0b,
                                              float* __restrict__ h1f, unsigned short* __restrict__ h1b) {
    int i = blockIdx.x * 256 + threadIdx.x;   // grid covers exactly NB*NH = 32768
    float v0 = hid[i];
    float v1 = hid[NB * NH + i];
    h0f[i] = v0; h0b[i] = f2bf(v0);
    h1f[i] = v1; h1b[i] = f2bf(v1);
}

// ---------------- bf16 NT GEMM: C[M][N] = A[M][K] * W[N][K]^T + bias ----------------
// K fixed = 1024. BM=BN=128, BK=32. 256 threads = 4 waves (2x2 of 64x64).
template<bool OUT_F32>
__global__ __launch_bounds__(256) void gemm_nt(const unsigned short* __restrict__ A,
                                               const unsigned short* __restrict__ W,
                                               const float* __restrict__ bias,
                                               void* __restrict__ C, int M, int N) {
    __shared__ short As[128][40];   // +8 pad breaks pow2 bank stride
    __shared__ short Bs[128][40];

    int tid  = threadIdx.x;
    int nblk = N >> 7;
    int bn   = blockIdx.x % nblk;
    int bm   = blockIdx.x / nblk;
    int lane = tid & 63;
    int w    = tid >> 6;
    int wm   = w >> 1, wn = w & 1;
    int lr   = lane & 15, lk = lane >> 4;

    f32x4 acc[4][4];
#pragma unroll
    for (int i = 0; i < 4; i++)
#pragma unroll
        for (int j = 0; j < 4; j++) acc[i][j] = (f32x4){0.f, 0.f, 0.f, 0.f};

    const short* Ag = (const short*)A;
    const short* Wg = (const short*)W;

    int r0 = tid >> 2;            // 0..63
    int kc = (tid & 3) * 8;       // 0,8,16,24

    for (int k0 = 0; k0 < 1024; k0 += 32) {
        __syncthreads();
#pragma unroll
        for (int jj = 0; jj < 2; jj++) {
            int row = r0 + jj * 64;
            *(short8*)&As[row][kc] = *(const short8*)&Ag[(size_t)(bm * 128 + row) * 1024 + k0 + kc];
            *(short8*)&Bs[row][kc] = *(const short8*)&Wg[(size_t)(bn * 128 + row) * 1024 + k0 + kc];
        }
        __syncthreads();

        short8 af[4], bf[4];
#pragma unroll
        for (int mi = 0; mi < 4; mi++) af[mi] = *(const short8*)&As[wm * 64 + mi * 16 + lr][lk * 8];
#pragma unroll
        for (int ni = 0; ni < 4; ni++) bf[ni] = *(const short8*)&Bs[wn * 64 + ni * 16 + lr][lk * 8];
#pragma unroll
        for (int mi = 0; mi < 4; mi++)
#pragma unroll
            for (int ni = 0; ni < 4; ni++)
                acc[mi][ni] = __builtin_amdgcn_mfma_f32_16x16x32_bf16(af[mi], bf[ni], acc[mi][ni], 0, 0, 0);
    }

    // epilogue: D row = (lane>>4)*4 + reg, col = lane&15  [m89-verified]
#pragma unroll
    for (int mi = 0; mi < 4; mi++) {
#pragma unroll
        for (int ni = 0; ni < 4; ni++) {
            int gr = bm * 128 + wm * 64 + mi * 16 + lk * 4;
            int gc = bn * 128 + wn * 64 + ni * 16 + lr;
            float bv = bias[gc];
#pragma unroll
            for (int r = 0; r < 4; r++) {
                float v = acc[mi][ni][r] + bv;
                if (OUT_F32) ((float*)C)[(size_t)(gr + r) * N + gc] = v;
                else         ((unsigned short*)C)[(size_t)(gr + r) * N + gc] = f2bf(v);
            }
        }
    }
}

// ---------------- one GRU time step ----------------
// grid 64 WGs x 192 threads (3 waves). WG owns 16 h-columns (j0..j0+15);
// wave g computes hp for gate g over [32 batches x 16 cols] via MFMA 16x16x32.
__global__ __launch_bounds__(192) void gru_step(const unsigned short* __restrict__ h_in_b,
                                                const float* __restrict__ h_in_f,
                                                unsigned short* __restrict__ h_out_b,
                                                float* __restrict__ h_out_f,
                                                const unsigned short* __restrict__ w_hh,
                                                const float* __restrict__ b_hh,
                                                const void* __restrict__ xp, int xp_f32,
                                                int t,
                                                unsigned short* __restrict__ y_b,
                                                float* __restrict__ y_f) {
    __shared__ float hp[3][32][16];

    int tid  = threadIdx.x;
    int wave = tid >> 6;          // 0..2 == gate {r,z,n}
    int lane = tid & 63;
    int lr   = lane & 15, lk = lane >> 4;
    int j0   = blockIdx.x * 16;

    const short* hb = (const short*)h_in_b;
    const short* wb = (const short*)w_hh;

    f32x4 acc0 = (f32x4){0.f, 0.f, 0.f, 0.f};
    f32x4 acc1 = (f32x4){0.f, 0.f, 0.f, 0.f};
    size_t wrow = (size_t)(wave * 1024 + j0 + lr) * 1024;

#pragma unroll 4
    for (int kt = 0; kt < 32; kt++) {
        int k = kt * 32 + lk * 8;
        short8 a0 = *(const short8*)&hb[lr * 1024 + k];
        short8 a1 = *(const short8*)&hb[(lr + 16) * 1024 + k];
        short8 b  = *(const short8*)&wb[wrow + k];
        acc0 = __builtin_amdgcn_mfma_f32_16x16x32_bf16(a0, b, acc0, 0, 0, 0);
        acc1 = __builtin_amdgcn_mfma_f32_16x16x32_bf16(a1, b, acc1, 0, 0, 0);
    }
#pragma unroll
    for (int r = 0; r < 4; r++) {
        hp[wave][lk * 4 + r][lr]      = acc0[r];
        hp[wave][16 + lk * 4 + r][lr] = acc1[r];
    }
    __syncthreads();

    // gate fusion over 512 elements (32 batches x 16 cols)
    for (int e = tid; e < 512; e += 192) {
        int b_ = e >> 4, c = e & 15;
        int gc = j0 + c;
        float hr = hp[0][b_][c] + b_hh[gc];
        float hz = hp[1][b_][c] + b_hh[1024 + gc];
        float hn = hp[2][b_][c] + b_hh[2048 + gc];

        size_t xbase = (size_t)b_ * (NT * G3) + (size_t)t * G3;
        float xr, xz, xn;
        if (xp_f32) {
            const float* xf = (const float*)xp;
            xr = xf[xbase + gc]; xz = xf[xbase + 1024 + gc]; xn = xf[xbase + 2048 + gc];
        } else {
            const unsigned short* xh = (const unsigned short*)xp;
            xr = bf2f(xh[xbase + gc]); xz = bf2f(xh[xbase + 1024 + gc]); xn = bf2f(xh[xbase + 2048 + gc]);
        }
        float r = 1.f / (1.f + __expf(-(xr + hr)));
        float z = 1.f / (1.f + __expf(-(xz + hz)));
        float n = tanhf(xn + r * hn);
        float hprev = h_in_f[b_ * 1024 + gc];
        float hnew  = (1.f - z) * n + z * hprev;

        h_out_f[b_ * 1024 + gc] = hnew;
        h_out_b[b_ * 1024 + gc] = f2bf(hnew);
        size_t yidx = (size_t)b_ * (NT * NH) + (size_t)t * NH + gc;
        if (y_b) y_b[yidx] = f2bf(hnew);
        if (y_f) y_f[yidx] = hnew;
    }
}

// ---------------- tail: final hidden states -> d_out ----------------
__global__ __launch_bounds__(256) void copy_h(const float* __restrict__ h0,
                                              const float* __restrict__ h1,
                                              float* __restrict__ out) {
    int i = blockIdx.x * 256 + threadIdx.x;  // grid covers exactly 32768
    out[i] = h0[i];
    out[NB * NH + i] = h1[i];
}

extern "C" void kernel_launch(void* const* d_in, const int* in_sizes, int n_in,
                              void* d_out, int out_size, void* d_ws, size_t ws_size,
                              hipStream_t stream) {
    (void)in_sizes; (void)n_in; (void)out_size;

    const float* x     = (const float*)d_in[0];
    const float* hid   = (const float*)d_in[1];
    const float* w_ih0 = (const float*)d_in[2];
    const float* w_hh0 = (const float*)d_in[3];
    const float* b_ih0 = (const float*)d_in[4];
    const float* b_hh0 = (const float*)d_in[5];
    const float* w_ih1 = (const float*)d_in[6];
    const float* w_hh1 = (const float*)d_in[7];
    const float* b_ih1 = (const float*)d_in[8];
    const float* b_hh1 = (const float*)d_in[9];
    float* out = (float*)d_out;

    char* ws = (char*)d_ws;
    size_t off = 0;
    auto alloc = [&](size_t bytes) -> void* {
        void* p = ws + off;
        off += (bytes + 255) & ~(size_t)255;
        return p;
    };

    const size_t M = (size_t)NB * NT;  // 16384
    // decide xp precision by available workspace
    size_t restBytes = M * 1024 * 2 * 2          // x_b + y0_b
                     + (size_t)4 * G3 * 1024 * 2 // 4 bf16 weight copies
                     + (size_t)2 * 1024 * 1024;  // h buffers + align slack
    bool XPF = ws_size >= (M * G3 * 4 + restBytes);

    void*           xp    = alloc(XPF ? M * G3 * 4 : M * G3 * 2);
    unsigned short* x_b   = (unsigned short*)alloc(M * 1024 * 2);
    unsigned short* y0_b  = (unsigned short*)alloc(M * 1024 * 2);
    unsigned short* wih0b = (unsigned short*)alloc((size_t)G3 * 1024 * 2);
    unsigned short* whh0b = (unsigned short*)alloc((size_t)G3 * 1024 * 2);
    unsigned short* wih1b = (unsigned short*)alloc((size_t)G3 * 1024 * 2);
    unsigned short* whh1b = (unsigned short*)alloc((size_t)G3 * 1024 * 2);
    float*          hf0[2]; unsigned short* hb0[2];
    float*          hf1[2]; unsigned short* hb1[2];
    for (int i = 0; i < 2; i++) { hf0[i] = (float*)alloc(NB * NH * 4); hb0[i] = (unsigned short*)alloc(NB * NH * 2); }
    for (int i = 0; i < 2; i++) { hf1[i] = (float*)alloc(NB * NH * 4); hb1[i] = (unsigned short*)alloc(NB * NH * 2); }

    // --- conversions ---
    cvt_bf16_v4<<<1024, 256, 0, stream>>>((const float4*)x,     (us4*)x_b,   (int)(M * 1024 / 4));
    cvt_bf16_v4<<<512,  256, 0, stream>>>((const float4*)w_ih0, (us4*)wih0b, G3 * 1024 / 4);
    cvt_bf16_v4<<<512,  256, 0, stream>>>((const float4*)w_hh0, (us4*)whh0b, G3 * 1024 / 4);
    cvt_bf16_v4<<<512,  256, 0, stream>>>((const float4*)w_ih1, (us4*)wih1b, G3 * 1024 / 4);
    cvt_bf16_v4<<<512,  256, 0, stream>>>((const float4*)w_hh1, (us4*)whh1b, G3 * 1024 / 4);
    init_h<<<NB * NH / 256, 256, 0, stream>>>(hid, hf0[0], hb0[0], hf1[0], hb1[0]);

    const int gemm_grid = (int)(M / 128) * (G3 / 128);  // 128*24 = 3072

    // --- layer 0 ---
    if (XPF) gemm_nt<true ><<<gemm_grid, 256, 0, stream>>>(x_b, wih0b, b_ih0, xp, (int)M, G3);
    else     gemm_nt<false><<<gemm_grid, 256, 0, stream>>>(x_b, wih0b, b_ih0, xp, (int)M, G3);
    for (int t = 0; t < NT; t++) {
        gru_step<<<64, 192, 0, stream>>>(hb0[t & 1], hf0[t & 1], hb0[(t + 1) & 1], hf0[(t + 1) & 1],
                                         whh0b, b_hh0, xp, (int)XPF, t, y0_b, nullptr);
    }

    // --- layer 1 ---
    if (XPF) gemm_nt<true ><<<gemm_grid, 256, 0, stream>>>(y0_b, wih1b, b_ih1, xp, (int)M, G3);
    else     gemm_nt<false><<<gemm_grid, 256, 0, stream>>>(y0_b, wih1b, b_ih1, xp, (int)M, G3);
    for (int t = 0; t < NT; t++) {
        gru_step<<<64, 192, 0, stream>>>(hb1[t & 1], hf1[t & 1], hb1[(t + 1) & 1], hf1[(t + 1) & 1],
                                         whh1b, b_hh1, xp, (int)XPF, t, nullptr, out);
    }

    copy_h<<<NB * NH / 256, 256, 0, stream>>>(hf0[0], hf1[0], out + (size_t)NB * NT * NH);
}

// Round 2
// 10242.487 us; speedup vs baseline: 1.3981x; 1.3981x over previous
//
#include <hip/hip_runtime.h>
#include <hip/hip_bf16.h>

#define NB 32
#define NT 512
#define NH 1024
#define G3 3072
#define NWG 128
#define PK_LDS (98304 + 16384 + 8192)   // w_hh blob + partials + hp

typedef __attribute__((ext_vector_type(8))) short short8;
typedef __attribute__((ext_vector_type(4))) float f32x4;
typedef __attribute__((ext_vector_type(4))) unsigned short us4;

static __device__ __forceinline__ unsigned short f2bf(float f) {
    union { float f; unsigned u; } v; v.f = f;
    if ((v.u & 0x7fffffffu) > 0x7f800000u) return (unsigned short)((v.u >> 16) | 0x0040u);
    unsigned u = v.u + 0x7fffu + ((v.u >> 16) & 1u);
    return (unsigned short)(u >> 16);
}

// ---------------- f32 -> bf16 conversion (vectorized) ----------------
__global__ __launch_bounds__(256) void cvt_bf16_v4(const float4* __restrict__ src,
                                                   us4* __restrict__ dst, int n4) {
    for (int i = blockIdx.x * 256 + threadIdx.x; i < n4; i += gridDim.x * 256) {
        float4 v = src[i];
        us4 o;
        o.x = f2bf(v.x); o.y = f2bf(v.y); o.z = f2bf(v.z); o.w = f2bf(v.w);
        dst[i] = o;
    }
}

// ---------------- x [B][T][D] f32 -> xt [T][B][D] bf16 ----------------
__global__ __launch_bounds__(256) void txp_x(const float4* __restrict__ x, us4* __restrict__ xt) {
    const int total = NT * NB * 256;   // in float4 units
    for (int i = blockIdx.x * 256 + threadIdx.x; i < total; i += gridDim.x * 256) {
        int b = i / (NT * 256);
        int rem = i - b * (NT * 256);
        int t = rem >> 8;
        int d4 = rem & 255;
        float4 v = x[i];   // i == ((b*NT+t)*256 + d4)
        us4 o;
        o.x = f2bf(v.x); o.y = f2bf(v.y); o.z = f2bf(v.z); o.w = f2bf(v.w);
        xt[((size_t)t * NB + b) * 256 + d4] = o;
    }
}

// ---------------- init hidden state (f32 master + bf16 shadow) ----------------
__global__ __launch_bounds__(256) void init_h(const float* __restrict__ hid,
                                              float* __restrict__ h0f, unsigned short* __restrict__ h0b,
                                              float* __restrict__ h1f, unsigned short* __restrict__ h1b) {
    int i = blockIdx.x * 256 + threadIdx.x;   // grid covers exactly NB*NH = 32768
    float v0 = hid[i];
    float v1 = hid[NB * NH + i];
    h0f[i] = v0; h0b[i] = f2bf(v0);
    h1f[i] = v1; h1b[i] = f2bf(v1);
}

// ---------------- persistent 2-layer GRU ----------------
// 128 WGs x 256 thr. WG = (layer, 16 h-cols). Waves = (m-tile, K-half).
// Per interval i: layer0 computes step t=i, layer1 computes step t=i-1
// (reads y0[i-1] produced last interval). One device barrier per interval.
__global__ __launch_bounds__(256, 1) void gru_persistent(
    const unsigned short* __restrict__ xt,      // [T][B][1024] bf16
    unsigned short* __restrict__ y0b,           // [T][B][1024] bf16
    const unsigned short* __restrict__ wih0, const unsigned short* __restrict__ whh0,
    const unsigned short* __restrict__ wih1, const unsigned short* __restrict__ whh1,
    const float* __restrict__ bih0, const float* __restrict__ bhh0,
    const float* __restrict__ bih1, const float* __restrict__ bhh1,
    float* __restrict__ hf00, float* __restrict__ hf01,
    unsigned short* __restrict__ hb00, unsigned short* __restrict__ hb01,
    float* __restrict__ hf10, float* __restrict__ hf11,
    unsigned short* __restrict__ hb10, unsigned short* __restrict__ hb11,
    float* __restrict__ out,                    // y1 [B][T][1024] f32, then h [2][B][1024]
    int* bar_cnt, int* bar_flag)
{
    extern __shared__ char lds[];
    short* blob = (short*)lds;                        // 98304 B: w_hh fragment blobs
    float* part = (float*)(lds + 98304);              // 16384 B: per-wave partials
    float* hpf  = (float*)(lds + 98304 + 16384);      // 8192 B: reduced pre-acts [4][32][16]

    const int tid  = threadIdx.x;
    const int lane = tid & 63;
    const int wv   = tid >> 6;      // 0..3
    const int kh   = wv & 1;        // K-half
    const int mt   = wv >> 1;       // M-tile (batch 0-15 / 16-31)
    const int lr   = lane & 15;
    const int lq   = lane >> 4;

    const int wg  = blockIdx.x;
    const int lay = wg >> 6;
    const int j0  = (wg & 63) * 16;

    const unsigned short* wih = lay ? wih1 : wih0;
    const unsigned short* whh = lay ? whh1 : whh0;
    const float* bih = lay ? bih1 : bih0;
    const float* bhh = lay ? bhh1 : bhh0;
    float* hf[2]; unsigned short* hb[2];
    if (lay == 0) { hf[0] = hf00; hf[1] = hf01; hb[0] = hb00; hb[1] = hb01; }
    else          { hf[0] = hf10; hf[1] = hf11; hb[0] = hb10; hb[1] = hb11; }

    // ---- stage w_hh rows {g*1024+j0 .. +16} into LDS, fragment-blob order ----
    // chunk index c = (g*32+kt)*64 + q*16 + col ; contents w[g*1024+j0+col][kt*32+q*8 ..+8]
    for (int c = tid; c < 6144; c += 256) {
        int g   = c >> 11;
        int rem = c & 2047;
        int kt  = rem >> 6;
        int q   = (rem >> 4) & 3;
        int col = rem & 15;
        *(short8*)(blob + c * 8) =
            *(const short8*)((const short*)whh + (size_t)(g * 1024 + j0 + col) * 1024 + kt * 32 + q * 8);
    }
    __syncthreads();

    const int aoff = (mt * 16 + lr) * 1024 + lq * 8;               // lane offset into [32][1024] slab
    const short* wiB = (const short*)wih + (size_t)(j0 + lr) * 1024 + lq * 8;

    for (int i = 0; i <= NT; ++i) {
        const bool active = lay ? (i >= 1) : (i < NT);
        const int t = lay ? (i - 1) : i;
        if (active) {
            const unsigned short* Asrc = lay ? (const unsigned short*)y0b : xt;
            const short* Ap = (const short*)(Asrc + (size_t)t * NB * 1024) + aoff;
            const short* Ah = (const short*)hb[t & 1] + aoff;

            f32x4 acc0 = {0.f,0.f,0.f,0.f};   // r (proj+rec)
            f32x4 acc1 = {0.f,0.f,0.f,0.f};   // z (proj+rec)
            f32x4 acc2 = {0.f,0.f,0.f,0.f};   // n proj only
            f32x4 acc3 = {0.f,0.f,0.f,0.f};   // n rec only

#pragma unroll 8
            for (int kk = 0; kk < 16; ++kk) {
                const int kt = kh * 16 + kk;
                short8 a  = *(const short8*)(Ap + kt * 32);
                short8 b0 = *(const short8*)(wiB + kt * 32);
                short8 b1 = *(const short8*)(wiB + 1024 * 1024 + kt * 32);
                short8 b2 = *(const short8*)(wiB + 2 * 1024 * 1024 + kt * 32);
                acc0 = __builtin_amdgcn_mfma_f32_16x16x32_bf16(a, b0, acc0, 0, 0, 0);
                acc1 = __builtin_amdgcn_mfma_f32_16x16x32_bf16(a, b1, acc1, 0, 0, 0);
                acc2 = __builtin_amdgcn_mfma_f32_16x16x32_bf16(a, b2, acc2, 0, 0, 0);
            }
#pragma unroll 8
            for (int kk = 0; kk < 16; ++kk) {
                const int kt = kh * 16 + kk;
                short8 a  = *(const short8*)(Ah + kt * 32);
                short8 c0 = *(const short8*)(blob + kt * 512 + lane * 8);
                short8 c1 = *(const short8*)(blob + (32 + kt) * 512 + lane * 8);
                short8 c2 = *(const short8*)(blob + (64 + kt) * 512 + lane * 8);
                acc0 = __builtin_amdgcn_mfma_f32_16x16x32_bf16(a, c0, acc0, 0, 0, 0);
                acc1 = __builtin_amdgcn_mfma_f32_16x16x32_bf16(a, c1, acc1, 0, 0, 0);
                acc3 = __builtin_amdgcn_mfma_f32_16x16x32_bf16(a, c2, acc3, 0, 0, 0);
            }

            *(f32x4*)(part + ((wv * 4 + 0) * 64 + lane) * 4) = acc0;
            *(f32x4*)(part + ((wv * 4 + 1) * 64 + lane) * 4) = acc1;
            *(f32x4*)(part + ((wv * 4 + 2) * 64 + lane) * 4) = acc2;
            *(f32x4*)(part + ((wv * 4 + 3) * 64 + lane) * 4) = acc3;
            __syncthreads();

            // reduce K-halves: hpf[g][b][c] = sum_kh part
            for (int eo = tid; eo < 2048; eo += 256) {
                int g2 = eo >> 9, b = (eo >> 4) & 31, c = eo & 15;
                int m = b >> 4, r = b & 3, l = ((b >> 2) & 3) * 16 + c;
                float v = part[(((m * 2 + 0) * 4 + g2) * 64 + l) * 4 + r]
                        + part[(((m * 2 + 1) * 4 + g2) * 64 + l) * 4 + r];
                hpf[eo] = v;
            }
            __syncthreads();

            float* hfin  = hf[t & 1];
            float* hfout = hf[(t + 1) & 1];
            unsigned short* hbout = hb[(t + 1) & 1];
            for (int e = tid; e < 512; e += 256) {
                int b = e >> 4, c = e & 15, gc = j0 + c;
                float pr  = hpf[e];
                float pz  = hpf[512 + e];
                float pxn = hpf[1024 + e];
                float phn = hpf[1536 + e];
                float r = 1.f / (1.f + __expf(-(pr + bih[gc] + bhh[gc])));
                float z = 1.f / (1.f + __expf(-(pz + bih[1024 + gc] + bhh[1024 + gc])));
                float n = tanhf(pxn + bih[2048 + gc] + r * (phn + bhh[2048 + gc]));
                float hprev = hfin[b * 1024 + gc];
                float hnew  = (1.f - z) * n + z * hprev;
                hfout[b * 1024 + gc] = hnew;
                hbout[b * 1024 + gc] = f2bf(hnew);
                if (lay == 0) y0b[((size_t)t * NB + b) * 1024 + gc] = f2bf(hnew);
                else          out[((size_t)b * NT + t) * 1024 + gc] = hnew;
                if (t == NT - 1)
                    out[(size_t)NB * NT * 1024 + (size_t)lay * NB * 1024 + b * 1024 + gc] = hnew;
            }
        }

        if (i < NT) {
            __syncthreads();
            if (tid == 0) {
                int old = __hip_atomic_fetch_add(bar_cnt, 1, __ATOMIC_ACQ_REL, __HIP_MEMORY_SCOPE_AGENT);
                if (old == (i + 1) * NWG - 1) {
                    __hip_atomic_store(bar_flag, i + 1, __ATOMIC_RELEASE, __HIP_MEMORY_SCOPE_AGENT);
                } else {
                    while (__hip_atomic_load(bar_flag, __ATOMIC_ACQUIRE, __HIP_MEMORY_SCOPE_AGENT) < i + 1)
                        __builtin_amdgcn_s_sleep(2);
                }
            }
            __syncthreads();
        }
    }
}

extern "C" void kernel_launch(void* const* d_in, const int* in_sizes, int n_in,
                              void* d_out, int out_size, void* d_ws, size_t ws_size,
                              hipStream_t stream) {
    (void)in_sizes; (void)n_in; (void)out_size; (void)ws_size;

    const float* x     = (const float*)d_in[0];
    const float* hid   = (const float*)d_in[1];
    const float* w_ih0 = (const float*)d_in[2];
    const float* w_hh0 = (const float*)d_in[3];
    const float* b_ih0 = (const float*)d_in[4];
    const float* b_hh0 = (const float*)d_in[5];
    const float* w_ih1 = (const float*)d_in[6];
    const float* w_hh1 = (const float*)d_in[7];
    const float* b_ih1 = (const float*)d_in[8];
    const float* b_hh1 = (const float*)d_in[9];
    float* out = (float*)d_out;

    char* ws = (char*)d_ws;
    size_t off = 0;
    auto alloc = [&](size_t bytes) -> void* {
        void* p = ws + off;
        off += (bytes + 255) & ~(size_t)255;
        return p;
    };

    unsigned short* xtb   = (unsigned short*)alloc((size_t)NT * NB * 1024 * 2);
    unsigned short* y0b   = (unsigned short*)alloc((size_t)NT * NB * 1024 * 2);
    unsigned short* wih0b = (unsigned short*)alloc((size_t)G3 * 1024 * 2);
    unsigned short* whh0b = (unsigned short*)alloc((size_t)G3 * 1024 * 2);
    unsigned short* wih1b = (unsigned short*)alloc((size_t)G3 * 1024 * 2);
    unsigned short* whh1b = (unsigned short*)alloc((size_t)G3 * 1024 * 2);
    float*          hf0[2]; unsigned short* hb0[2];
    float*          hf1[2]; unsigned short* hb1[2];
    for (int i = 0; i < 2; i++) { hf0[i] = (float*)alloc(NB * NH * 4); hb0[i] = (unsigned short*)alloc(NB * NH * 2); }
    for (int i = 0; i < 2; i++) { hf1[i] = (float*)alloc(NB * NH * 4); hb1[i] = (unsigned short*)alloc(NB * NH * 2); }
    int* bar = (int*)alloc(256);

    // --- conversions / init ---
    txp_x<<<2048, 256, 0, stream>>>((const float4*)x, (us4*)xtb);
    cvt_bf16_v4<<<512, 256, 0, stream>>>((const float4*)w_ih0, (us4*)wih0b, G3 * 1024 / 4);
    cvt_bf16_v4<<<512, 256, 0, stream>>>((const float4*)w_hh0, (us4*)whh0b, G3 * 1024 / 4);
    cvt_bf16_v4<<<512, 256, 0, stream>>>((const float4*)w_ih1, (us4*)wih1b, G3 * 1024 / 4);
    cvt_bf16_v4<<<512, 256, 0, stream>>>((const float4*)w_hh1, (us4*)whh1b, G3 * 1024 / 4);
    init_h<<<NB * NH / 256, 256, 0, stream>>>(hid, hf0[0], hb0[0], hf1[0], hb1[0]);
    hipMemsetAsync(bar, 0, 256, stream);

    // --- persistent recurrence (both layers, wavefront-pipelined) ---
    (void)hipFuncSetAttribute((const void*)gru_persistent,
                              hipFuncAttributeMaxDynamicSharedMemorySize, PK_LDS);
    gru_persistent<<<NWG, 256, PK_LDS, stream>>>(
        xtb, y0b, wih0b, whh0b, wih1b, whh1b,
        b_ih0, b_hh0, b_ih1, b_hh1,
        hf0[0], hf0[1], hb0[0], hb0[1],
        hf1[0], hf1[1], hb1[0], hb1[1],
        out, bar, bar + 32);
}

// Round 3
// 7837.696 us; speedup vs baseline: 1.8270x; 1.3068x over previous
//
#include <hip/hip_runtime.h>
#include <hip/hip_bf16.h>

#define NB 32
#define NT 512
#define NH 1024
#define G3 3072
#define NWG 128
#define PK_LDS (98304 + 16384 + 8192)   // w_hh blob + partials + hp

typedef __attribute__((ext_vector_type(8))) short short8;
typedef __attribute__((ext_vector_type(4))) float f32x4;
typedef __attribute__((ext_vector_type(4))) unsigned short us4;

static __device__ __forceinline__ unsigned short f2bf(float f) {
    union { float f; unsigned u; } v; v.f = f;
    if ((v.u & 0x7fffffffu) > 0x7f800000u) return (unsigned short)((v.u >> 16) | 0x0040u);
    unsigned u = v.u + 0x7fffu + ((v.u >> 16) & 1u);
    return (unsigned short)(u >> 16);
}

// ---------------- f32 -> bf16 conversion (vectorized) ----------------
__global__ __launch_bounds__(256) void cvt_bf16_v4(const float4* __restrict__ src,
                                                   us4* __restrict__ dst, int n4) {
    for (int i = blockIdx.x * 256 + threadIdx.x; i < n4; i += gridDim.x * 256) {
        float4 v = src[i];
        us4 o;
        o.x = f2bf(v.x); o.y = f2bf(v.y); o.z = f2bf(v.z); o.w = f2bf(v.w);
        dst[i] = o;
    }
}

// ---------------- x [B][T][D] f32 -> xt [T][B][D] bf16 ----------------
__global__ __launch_bounds__(256) void txp_x(const float4* __restrict__ x, us4* __restrict__ xt) {
    const int total = NT * NB * 256;   // in float4 units
    for (int i = blockIdx.x * 256 + threadIdx.x; i < total; i += gridDim.x * 256) {
        int b = i / (NT * 256);
        int rem = i - b * (NT * 256);
        int t = rem >> 8;
        int d4 = rem & 255;
        float4 v = x[i];   // i == ((b*NT+t)*256 + d4)
        us4 o;
        o.x = f2bf(v.x); o.y = f2bf(v.y); o.z = f2bf(v.z); o.w = f2bf(v.w);
        xt[((size_t)t * NB + b) * 256 + d4] = o;
    }
}

// ---------------- init hidden state (f32 master + bf16 shadow) ----------------
__global__ __launch_bounds__(256) void init_h(const float* __restrict__ hid,
                                              float* __restrict__ h0f, unsigned short* __restrict__ h0b,
                                              float* __restrict__ h1f, unsigned short* __restrict__ h1b) {
    int i = blockIdx.x * 256 + threadIdx.x;   // grid covers exactly NB*NH = 32768
    float v0 = hid[i];
    float v1 = hid[NB * NH + i];
    h0f[i] = v0; h0b[i] = f2bf(v0);
    h1f[i] = v1; h1b[i] = f2bf(v1);
}

// ---------------- persistent 2-layer GRU ----------------
// 128 WGs x 256 thr. WG = (layer, 16 h-cols). Waves = (m-tile, K-half).
// Contention-free barrier: per-WG sequence flags (release-store arrival,
// wave0 polls 64 peer flags, syncthreads broadcast). Layer 1 additionally
// waits on layer 0's flags for y0[t]; layer 0 never waits on layer 1.
__global__ __launch_bounds__(256, 1) void gru_persistent(
    const unsigned short* __restrict__ xt,      // [T][B][1024] bf16
    unsigned short* __restrict__ y0b,           // [T][B][1024] bf16
    const unsigned short* __restrict__ wih0, const unsigned short* __restrict__ whh0,
    const unsigned short* __restrict__ wih1, const unsigned short* __restrict__ whh1,
    const float* __restrict__ bih0, const float* __restrict__ bhh0,
    const float* __restrict__ bih1, const float* __restrict__ bhh1,
    float* __restrict__ hf00, float* __restrict__ hf01,
    unsigned short* __restrict__ hb00, unsigned short* __restrict__ hb01,
    float* __restrict__ hf10, float* __restrict__ hf11,
    unsigned short* __restrict__ hb10, unsigned short* __restrict__ hb11,
    float* __restrict__ out,                    // y1 [B][T][1024] f32, then h [2][B][1024]
    int* __restrict__ flags)                    // fl0 = flags, fl1 = flags + 64*32
{
    extern __shared__ char lds[];
    short* blob = (short*)lds;                        // 98304 B: w_hh fragment blobs
    float* part = (float*)(lds + 98304);              // 16384 B: per-wave partials
    float* hpf  = (float*)(lds + 98304 + 16384);      // 8192 B: reduced pre-acts [4][32][16]

    const int tid  = threadIdx.x;
    const int lane = tid & 63;
    const int wv   = tid >> 6;      // 0..3
    const int kh   = wv & 1;        // K-half
    const int mt   = wv >> 1;       // M-tile (batch 0-15 / 16-31)
    const int lr   = lane & 15;
    const int lq   = lane >> 4;

    const int wg   = blockIdx.x;
    const int lay  = wg >> 6;
    const int slot = wg & 63;
    const int j0   = slot * 16;

    int* fl0 = flags;
    int* fl1 = flags + 64 * 32;
    int* flown = lay ? fl1 : fl0;

    const unsigned short* wih = lay ? wih1 : wih0;
    const unsigned short* whh = lay ? whh1 : whh0;
    const float* bih = lay ? bih1 : bih0;
    const float* bhh = lay ? bhh1 : bhh0;
    float* hf[2]; unsigned short* hb[2];
    if (lay == 0) { hf[0] = hf00; hf[1] = hf01; hb[0] = hb00; hb[1] = hb01; }
    else          { hf[0] = hf10; hf[1] = hf11; hb[0] = hb10; hb[1] = hb11; }

    // ---- stage w_hh rows {g*1024+j0 .. +16} into LDS, fragment-blob order ----
    // chunk index c = (g*32+kt)*64 + q*16 + col ; contents w[g*1024+j0+col][kt*32+q*8 ..+8]
    for (int c = tid; c < 6144; c += 256) {
        int g   = c >> 11;
        int rem = c & 2047;
        int kt  = rem >> 6;
        int q   = (rem >> 4) & 3;
        int col = rem & 15;
        *(short8*)(blob + c * 8) =
            *(const short8*)((const short*)whh + (size_t)(g * 1024 + j0 + col) * 1024 + kt * 32 + q * 8);
    }
    __syncthreads();

    const int aoff = (mt * 16 + lr) * 1024 + lq * 8;               // lane offset into [32][1024] slab
    const short* wiB = (const short*)wih + (size_t)(j0 + lr) * 1024 + lq * 8;

    for (int t = 0; t < NT; ++t) {
        if (lay == 1) {
            // y0b[t] must be fully published by layer 0
            if (wv == 0) {
                const int* p = fl0 + lane * 32;
                while (__hip_atomic_load(p, __ATOMIC_ACQUIRE, __HIP_MEMORY_SCOPE_AGENT) < t + 1)
                    __builtin_amdgcn_s_sleep(1);
            }
            __syncthreads();
        }

        // ---- input-projection phase (independent of h_t) ----
        const short* Asrc = lay ? (const short*)y0b : (const short*)xt;
        const short* Ap = Asrc + (size_t)t * NB * 1024 + aoff;

        f32x4 acc0 = {0.f,0.f,0.f,0.f};   // r (proj+rec)
        f32x4 acc1 = {0.f,0.f,0.f,0.f};   // z (proj+rec)
        f32x4 acc2 = {0.f,0.f,0.f,0.f};   // n proj only
        f32x4 acc3 = {0.f,0.f,0.f,0.f};   // n rec only

#pragma unroll 8
        for (int kk = 0; kk < 16; ++kk) {
            const int kt = kh * 16 + kk;
            short8 a  = *(const short8*)(Ap + kt * 32);
            short8 b0 = *(const short8*)(wiB + kt * 32);
            short8 b1 = *(const short8*)(wiB + 1024 * 1024 + kt * 32);
            short8 b2 = *(const short8*)(wiB + 2 * 1024 * 1024 + kt * 32);
            acc0 = __builtin_amdgcn_mfma_f32_16x16x32_bf16(a, b0, acc0, 0, 0, 0);
            acc1 = __builtin_amdgcn_mfma_f32_16x16x32_bf16(a, b1, acc1, 0, 0, 0);
            acc2 = __builtin_amdgcn_mfma_f32_16x16x32_bf16(a, b2, acc2, 0, 0, 0);
        }

        // ---- wait for peers' h_t (overlapped with proj above) ----
        if (wv == 0) {
            const int* p = flown + lane * 32;
            while (__hip_atomic_load(p, __ATOMIC_ACQUIRE, __HIP_MEMORY_SCOPE_AGENT) < t)
                __builtin_amdgcn_s_sleep(1);
        }
        __syncthreads();

        // ---- recurrent phase ----
        const short* Ah = (const short*)hb[t & 1] + aoff;
#pragma unroll 8
        for (int kk = 0; kk < 16; ++kk) {
            const int kt = kh * 16 + kk;
            short8 a  = *(const short8*)(Ah + kt * 32);
            short8 c0 = *(const short8*)(blob + kt * 512 + lane * 8);
            short8 c1 = *(const short8*)(blob + (32 + kt) * 512 + lane * 8);
            short8 c2 = *(const short8*)(blob + (64 + kt) * 512 + lane * 8);
            acc0 = __builtin_amdgcn_mfma_f32_16x16x32_bf16(a, c0, acc0, 0, 0, 0);
            acc1 = __builtin_amdgcn_mfma_f32_16x16x32_bf16(a, c1, acc1, 0, 0, 0);
            acc3 = __builtin_amdgcn_mfma_f32_16x16x32_bf16(a, c2, acc3, 0, 0, 0);
        }

        *(f32x4*)(part + ((wv * 4 + 0) * 64 + lane) * 4) = acc0;
        *(f32x4*)(part + ((wv * 4 + 1) * 64 + lane) * 4) = acc1;
        *(f32x4*)(part + ((wv * 4 + 2) * 64 + lane) * 4) = acc2;
        *(f32x4*)(part + ((wv * 4 + 3) * 64 + lane) * 4) = acc3;
        __syncthreads();

        // reduce K-halves: hpf[g][b][c] = sum_kh part
        for (int eo = tid; eo < 2048; eo += 256) {
            int g2 = eo >> 9, b = (eo >> 4) & 31, c = eo & 15;
            int m = b >> 4, r = b & 3, l = ((b >> 2) & 3) * 16 + c;
            float v = part[(((m * 2 + 0) * 4 + g2) * 64 + l) * 4 + r]
                    + part[(((m * 2 + 1) * 4 + g2) * 64 + l) * 4 + r];
            hpf[eo] = v;
        }
        __syncthreads();

        float* hfin  = hf[t & 1];
        float* hfout = hf[(t + 1) & 1];
        unsigned short* hbout = hb[(t + 1) & 1];
        for (int e = tid; e < 512; e += 256) {
            int b = e >> 4, c = e & 15, gc = j0 + c;
            float pr  = hpf[e];
            float pz  = hpf[512 + e];
            float pxn = hpf[1024 + e];
            float phn = hpf[1536 + e];
            float r = 1.f / (1.f + __expf(-(pr + bih[gc] + bhh[gc])));
            float z = 1.f / (1.f + __expf(-(pz + bih[1024 + gc] + bhh[1024 + gc])));
            float n = tanhf(pxn + bih[2048 + gc] + r * (phn + bhh[2048 + gc]));
            float hprev = hfin[b * 1024 + gc];
            float hnew  = (1.f - z) * n + z * hprev;
            hfout[b * 1024 + gc] = hnew;
            hbout[b * 1024 + gc] = f2bf(hnew);
            if (lay == 0) y0b[((size_t)t * NB + b) * 1024 + gc] = f2bf(hnew);
            else          out[((size_t)b * NT + t) * 1024 + gc] = hnew;
            if (t == NT - 1)
                out[(size_t)NB * NT * 1024 + (size_t)lay * NB * 1024 + b * 1024 + gc] = hnew;
        }
        __syncthreads();

        if (tid == 0)
            __hip_atomic_store(flown + slot * 32, t + 1, __ATOMIC_RELEASE, __HIP_MEMORY_SCOPE_AGENT);
    }
}

extern "C" void kernel_launch(void* const* d_in, const int* in_sizes, int n_in,
                              void* d_out, int out_size, void* d_ws, size_t ws_size,
                              hipStream_t stream) {
    (void)in_sizes; (void)n_in; (void)out_size; (void)ws_size;

    const float* x     = (const float*)d_in[0];
    const float* hid   = (const float*)d_in[1];
    const float* w_ih0 = (const float*)d_in[2];
    const float* w_hh0 = (const float*)d_in[3];
    const float* b_ih0 = (const float*)d_in[4];
    const float* b_hh0 = (const float*)d_in[5];
    const float* w_ih1 = (const float*)d_in[6];
    const float* w_hh1 = (const float*)d_in[7];
    const float* b_ih1 = (const float*)d_in[8];
    const float* b_hh1 = (const float*)d_in[9];
    float* out = (float*)d_out;

    char* ws = (char*)d_ws;
    size_t off = 0;
    auto alloc = [&](size_t bytes) -> void* {
        void* p = ws + off;
        off += (bytes + 255) & ~(size_t)255;
        return p;
    };

    unsigned short* xtb   = (unsigned short*)alloc((size_t)NT * NB * 1024 * 2);
    unsigned short* y0b   = (unsigned short*)alloc((size_t)NT * NB * 1024 * 2);
    unsigned short* wih0b = (unsigned short*)alloc((size_t)G3 * 1024 * 2);
    unsigned short* whh0b = (unsigned short*)alloc((size_t)G3 * 1024 * 2);
    unsigned short* wih1b = (unsigned short*)alloc((size_t)G3 * 1024 * 2);
    unsigned short* whh1b = (unsigned short*)alloc((size_t)G3 * 1024 * 2);
    float*          hf0[2]; unsigned short* hb0[2];
    float*          hf1[2]; unsigned short* hb1[2];
    for (int i = 0; i < 2; i++) { hf0[i] = (float*)alloc(NB * NH * 4); hb0[i] = (unsigned short*)alloc(NB * NH * 2); }
    for (int i = 0; i < 2; i++) { hf1[i] = (float*)alloc(NB * NH * 4); hb1[i] = (unsigned short*)alloc(NB * NH * 2); }
    int* flags = (int*)alloc(2 * 64 * 32 * sizeof(int));   // 16 KB, 128B-spaced slots

    // --- conversions / init ---
    txp_x<<<2048, 256, 0, stream>>>((const float4*)x, (us4*)xtb);
    cvt_bf16_v4<<<512, 256, 0, stream>>>((const float4*)w_ih0, (us4*)wih0b, G3 * 1024 / 4);
    cvt_bf16_v4<<<512, 256, 0, stream>>>((const float4*)w_hh0, (us4*)whh0b, G3 * 1024 / 4);
    cvt_bf16_v4<<<512, 256, 0, stream>>>((const float4*)w_ih1, (us4*)wih1b, G3 * 1024 / 4);
    cvt_bf16_v4<<<512, 256, 0, stream>>>((const float4*)w_hh1, (us4*)whh1b, G3 * 1024 / 4);
    init_h<<<NB * NH / 256, 256, 0, stream>>>(hid, hf0[0], hb0[0], hf1[0], hb1[0]);
    hipMemsetAsync(flags, 0, 2 * 64 * 32 * sizeof(int), stream);

    // --- persistent recurrence (both layers, wavefront-pipelined) ---
    (void)hipFuncSetAttribute((const void*)gru_persistent,
                              hipFuncAttributeMaxDynamicSharedMemorySize, PK_LDS);
    gru_persistent<<<NWG, 256, PK_LDS, stream>>>(
        xtb, y0b, wih0b, whh0b, wih1b, whh1b,
        b_ih0, b_hh0, b_ih1, b_hh1,
        hf0[0], hf0[1], hb0[0], hb0[1],
        hf1[0], hf1[1], hb1[0], hb1[1],
        out, flags);
}